// Round 1
// baseline (132.454 us; speedup 1.0000x reference)
//
#include <hip/hip_runtime.h>

// EvalEig: 12288 independent 4-term linear recurrences (radial ODE solves),
// one thread per (energy,l) chain. Long (u_infty, 894 steps) and short
// (u_zero, 94 steps) chains in separate waves. Stores coalesced across lanes
// (position-major output layout). Second kernel applies the reference's
// energy-axis-reversed lfunc_out and writes output 0.

namespace {
constexpr int kNE   = 4096;
constexpr int kL    = 3;
constexpr int kNCH  = kNE * kL;     // 12288 chains
constexpr int kMatch = 100;

// c = 3/40*RD^2, k1 = 13/15*RD^2, k2 = 7/60*RD^2, RD = 0.1
constexpr float kC  = 3.0f / 40.0f * 0.01f;
constexpr float kK1 = 13.0f / 15.0f * 0.01f;
constexpr float kK2 = 7.0f / 60.0f * 0.01f;
}

__device__ __forceinline__ float rcp_nr(float x) {
    float r = __builtin_amdgcn_rcpf(x);
    return fmaf(fmaf(-x, r, 1.0f), r, r);   // one Newton step -> ~0.5 ulp
}

__global__ __launch_bounds__(64) void solve_kernel(const float* __restrict__ energy,
                                                   float* __restrict__ out,
                                                   float* __restrict__ ws)
{
    const int bid  = (int)blockIdx.x;
    const int lane = (int)threadIdx.x;
    const bool infty = bid < (kNCH / 64);                 // blocks 0..191 -> u_infty
    const int t  = (infty ? bid : bid - kNCH / 64) * 64 + lane;
    const int l  = t % 3;
    const int ei = t / 3;
    const float e    = energy[ei];
    const float negE = -e;
    const float ll1  = (float)(l * (l + 1));

    float* uzero = out + kNCH;
    float* uinf  = out + kNCH + (size_t)kMatch * kNCH;

    if (infty) {
        // ---- inward solve: reversed coords, w[j] at r = 100 - 0.1*j ----
        const float se  = sqrtf(fabsf(e));
        const float rfc = (l == 0) ? 1.0f : ((l == 1) ? (1.0f/3.0f) : (1.0f/15.0f));
        const float rt1 = (l == 0) ? (1.0f/3.0f) : ((l == 1) ? (1.0f/5.0f) : (1.0f/7.0f));
        const float rt2 = (l == 0) ? (1.0f/30.0f) : ((l == 1) ? (1.0f/70.0f) : (1.0f/126.0f));
        float p0,p1,p2,p3,p4;
        {
            float pw[5];
            #pragma unroll
            for (int k = 0; k < 5; ++k) {
                float rinf = 99.6f + 0.1f * (float)k;
                float x  = rinf * se;
                float xl = (l == 0) ? 1.0f : ((l == 1) ? x : x * x);
                float base = xl * rfc;
                float h  = x * x * 0.5f;
                pw[k] = rinf * (base * (1.0f + h * rt1 + (h * h) * rt2));
            }
            p0=pw[0]; p1=pw[1]; p2=pw[2]; p3=pw[3]; p4=pw[4];
        }
        uinf[(size_t)899 * kNCH + t] = p4;               // w[4] -> pos 899

        // factor ring f0..f3 = facrev[1..4] at r = 99.9, 99.8, 99.7, 99.6
        float f0, f1, f2, f3;
        {
            float i1 = rcp_nr(99.9f), i2 = rcp_nr(99.8f), i3 = rcp_nr(99.7f), i4 = rcp_nr(99.6f);
            f0 = fmaf(i1, fmaf(ll1, i1, -1.0f), negE);
            f1 = fmaf(i2, fmaf(ll1, i2, -1.0f), negE);
            f2 = fmaf(i3, fmaf(ll1, i3, -1.0f), negE);
            f3 = fmaf(i4, fmaf(ll1, i4, -1.0f), negE);
        }

        float acc4 = 0.0f, acc2 = 0.0f;                  // u^4-weighted / u^2 sums
        float* ptr = uinf + (size_t)898 * kNCH + t;      // w[j] -> pos 903-j
        #pragma unroll 4
        for (int j = 5; j <= 898; ++j) {
            float rm = fmaf((float)j, -0.1f, 100.0f);
            float ri = rcp_nr(rm);
            float f4 = fmaf(ri, fmaf(ll1, ri, -1.0f), negE);
            float dn = fmaf(-kC, f4, 1.0f);
            float iv = rcp_nr(dn);
            float a  = fmaf(kC  * f0, iv, -1.0f);
            float b  = fmaf(kK1 * f1, iv,  2.0f);
            float cc = fmaf(kK2 * f2, iv, -2.0f);
            float d  = fmaf(kK1 * f3, iv,  2.0f);
            float nw = fmaf(d, p4, fmaf(cc, p3, fmaf(b, p2, a * p1)));
            *ptr = nw; ptr -= kNCH;
            float v2 = nw * nw, v4 = v2 * v2;
            if (j >= 8) {                                // pos 5..895 regular weights
                int m = j & 3;                           // p%4: j%4=1->2, 2->1, 3->0, 0->3
                if (m == 1)      acc2 += v2;             // p%4==2 -> 12*u^2 (applied at end)
                else if (m == 3) acc4 += 14.0f * v4;     // p%4==0 interior
                else             acc4 += 32.0f * v4;     // p%4==1,3
            } else if (j == 7) {
                acc4 += 7.0f * v4;                       // pos 896: g4-only
            }                                            // j=5,6 (pos 898,897): weight 0
            f0 = f1; f1 = f2; f2 = f3; f3 = f4;
            p0 = p1; p1 = p2; p2 = p3; p3 = p4; p4 = nw;
        }
        // p0..p4 = w[894..898] -> output positions 0..4 (reflected head)
        uinf[(size_t)0 * kNCH + t] = p0;
        uinf[(size_t)1 * kNCH + t] = p1;
        uinf[(size_t)2 * kNCH + t] = p2;
        uinf[(size_t)3 * kNCH + t] = p3;
        uinf[(size_t)4 * kNCH + t] = p4;
        {
            float q0=p0*p0, q1=p1*p1, q2=p2*p2, q3=p3*p3, q4=p4*p4;
            acc4 += 7.0f  * q0*q0;    // pos 0
            acc4 += 32.0f * q1*q1;    // pos 1
            acc2 += q2;               // pos 2
            acc4 += 32.0f * q3*q3;    // pos 3
            acc4 += 14.0f * q4*q4;    // pos 4 (g0 and g4)
        }
        float integ = fmaf(12.0f, acc2, acc4) * (2.0f * 0.1f / 45.0f);
        float deriv = fmaf(25.0f, p0, fmaf(-48.0f, p1, fmaf(36.0f, p2,
                      fmaf(-16.0f, p3, 3.0f * p4)))) * (1.0f / 1.2f);
        ws[t]        = deriv / p0;            // lfunc_out (pre-reversal)
        ws[kNCH + t] = integ / (p0 * p0);     // integ_out / u_infty[0]^2
    } else {
        // ---- outward solve: u[j] at r = 0.1*(j+1) ----
        const float rdiv = (l == 0) ? 0.5f : ((l == 1) ? 0.25f : (1.0f/6.0f));
        float p0,p1,p2,p3,p4;
        {
            float pw[5];
            #pragma unroll
            for (int k = 0; k < 5; ++k) {
                float r = 0.1f * (float)(k + 1);
                float rl1 = (l == 0) ? r : ((l == 1) ? r*r : r*r*r);   // r^(l+1)
                pw[k] = rl1 - (rl1 * r) * rdiv;                        // - r^(l+2)/(2(l+1))
                uzero[(size_t)k * kNCH + t] = pw[k];
            }
            uzero[(size_t)5 * kNCH + t] = pw[4];        // duplicated point
            p0=pw[0]; p1=pw[1]; p2=pw[2]; p3=pw[3]; p4=pw[4];
        }
        float acc4, acc2;
        {
            float q0=p0*p0, q1=p1*p1, q2=p2*p2, q3=p3*p3, q4=p4*p4;
            acc4 = 7.0f*q0*q0 + 32.0f*q1*q1 + 32.0f*q3*q3
                 + 14.0f*q4*q4          // pos 4
                 + 32.0f*q4*q4;         // pos 5 (duplicate, p%4==1)
            acc2 = q2;                  // pos 2
        }
        float f0, f1, f2, f3;
        {
            float i1 = rcp_nr(0.2f), i2 = rcp_nr(0.3f), i3 = rcp_nr(0.4f), i4 = rcp_nr(0.5f);
            f0 = fmaf(i1, fmaf(ll1, i1, -1.0f), negE);
            f1 = fmaf(i2, fmaf(ll1, i2, -1.0f), negE);
            f2 = fmaf(i3, fmaf(ll1, i3, -1.0f), negE);
            f3 = fmaf(i4, fmaf(ll1, i4, -1.0f), negE);
        }
        float* ptr = uzero + (size_t)6 * kNCH + t;       // u[j] -> pos j+1
        #pragma unroll 4
        for (int j = 5; j <= 98; ++j) {
            float rm = fmaf((float)j, 0.1f, 0.1f);
            float ri = rcp_nr(rm);
            float f4 = fmaf(ri, fmaf(ll1, ri, -1.0f), negE);
            float dn = fmaf(-kC, f4, 1.0f);
            float iv = rcp_nr(dn);
            float a  = fmaf(kC  * f0, iv, -1.0f);
            float b  = fmaf(kK1 * f1, iv,  2.0f);
            float cc = fmaf(kK2 * f2, iv, -2.0f);
            float d  = fmaf(kK1 * f3, iv,  2.0f);
            float nw = fmaf(d, p4, fmaf(cc, p3, fmaf(b, p2, a * p1)));
            *ptr = nw; ptr += kNCH;
            float v2 = nw*nw, v4 = v2*v2;
            if (j <= 94) {                               // pos 6..95 regular
                int m = (j + 1) & 3;                     // = pos % 4
                if (m == 2)      acc2 += v2;
                else if (m == 0) acc4 += 14.0f * v4;
                else             acc4 += 32.0f * v4;
            } else if (j == 95) {
                acc4 += 7.0f * v4;                       // pos 96: g4-only
            }                                            // pos 97,98,99: weight 0
            f0 = f1; f1 = f2; f2 = f3; f3 = f4;
            p0 = p1; p1 = p2; p2 = p3; p3 = p4; p4 = nw;
        }
        // p0..p4 = u[94..98]; u_zero[-1] = u[98] = p4
        float integ = fmaf(12.0f, acc2, acc4) * (2.0f * 0.1f / 45.0f);
        float deriv = fmaf(25.0f, p4, fmaf(-48.0f, p3, fmaf(36.0f, p2,
                      fmaf(-16.0f, p1, 3.0f * p0)))) * (1.0f / 1.2f);
        ws[2 * kNCH + t] = deriv / p4;        // lfunc_in
        ws[3 * kNCH + t] = integ / (p4 * p4); // integ_in / u_zero[-1]^2
    }
}

__global__ __launch_bounds__(256) void final_kernel(const float* __restrict__ energy,
                                                    const float* __restrict__ ws,
                                                    float* __restrict__ out)
{
    int t = (int)blockIdx.x * 256 + (int)threadIdx.x;
    if (t >= kNCH) return;
    int l = t % 3, ei = t / 3;
    // reference applies [::-1] over the ENERGY axis to lfunc_out only
    float lf_out = ws[(kNE - 1 - ei) * 3 + l];
    float lf_in  = ws[2 * kNCH + t];
    float den    = ws[kNCH + t] + ws[3 * kNCH + t];
    out[t] = energy[ei] - (lf_out - lf_in) / den;
}

extern "C" void kernel_launch(void* const* d_in, const int* in_sizes, int n_in,
                              void* d_out, int out_size, void* d_ws, size_t ws_size,
                              hipStream_t stream) {
    (void)in_sizes; (void)n_in; (void)out_size; (void)ws_size;
    const float* energy = (const float*)d_in[0];
    float* out = (float*)d_out;
    float* ws  = (float*)d_ws;   // 4*12288 floats = 192 KB scratch
    solve_kernel<<<2 * (kNCH / 64), 64, 0, stream>>>(energy, out, ws);
    final_kernel<<<kNCH / 256, 256, 0, stream>>>(energy, ws, out);
}

// Round 2
// 91.850 us; speedup vs baseline: 1.4421x; 1.4421x over previous
//
#include <hip/hip_runtime.h>

// EvalEig: segmented transfer-matrix parallelization of the 894-step inward
// (u_infty) recurrence. 16 segments/chain x 12288 chains -> 3072 waves
// (vs 192 in round 1, which was latency-bound at 193 cyc/iter).
// Phase 1: per-segment 4x4 companion-product. Phase 2: per-chain serial
// combine (16 mat-vec applies, lanes 0..15 of wave 0). Phase 3: replay from
// exact segment-initial states + quadrature partials + LDS reduce.
// u_zero (94 steps) stays one-thread-per-chain in the first 48 blocks so it
// overlaps the heavy blocks.

namespace {
constexpr int kNE    = 4096;
constexpr int kNCH   = kNE * 3;        // 12288 chains
constexpr int kMatch = 100;
constexpr float kC   = 3.0f / 40.0f * 0.01f;
constexpr float kK1  = 13.0f / 15.0f * 0.01f;
constexpr float kK2  = 7.0f / 60.0f * 0.01f;
constexpr int kZeroBlocks = kNCH / 256;   // 48
constexpr int kInfBlocks  = kNCH / 16;    // 768 (16 chains/block x 16 segs)
}

__device__ __forceinline__ float rcp_nr(float x) {
    float r = __builtin_amdgcn_rcpf(x);
    return fmaf(fmaf(-x, r, 1.0f), r, r);
}

__global__ __launch_bounds__(256) void solve_kernel(const float* __restrict__ energy,
                                                    float* __restrict__ out,
                                                    float* __restrict__ ws)
{
    __shared__ float sP[16][16][16];   // [seg][chain][row*4+col]  16 KB
    __shared__ float sSt[16][16][4];   // segment initial states    4 KB
    __shared__ float sR4[16][16];      // quadrature partials (u^4 terms)
    __shared__ float sR2[16][16];      // quadrature partials (u^2 terms)

    const int bid = (int)blockIdx.x;
    const int tid = (int)threadIdx.x;
    float* uzero = out + kNCH;
    float* uinf  = out + kNCH + (size_t)kMatch * kNCH;

    if (bid < kZeroBlocks) {
        // ---------------- u_zero: outward solve, 94 steps, 1 thread/chain ----
        const int t  = bid * 256 + tid;
        const int l  = t % 3;
        const int ei = t / 3;
        const float e = energy[ei], negE = -e;
        const float ll1 = (float)(l * (l + 1));
        const float rdiv = (l == 0) ? 0.5f : ((l == 1) ? 0.25f : (1.0f/6.0f));
        float p0,p1,p2,p3,p4;
        {
            float pw[5];
            #pragma unroll
            for (int k = 0; k < 5; ++k) {
                float r = 0.1f * (float)(k + 1);
                float rl1 = (l == 0) ? r : ((l == 1) ? r*r : r*r*r);
                pw[k] = rl1 - (rl1 * r) * rdiv;
                uzero[(size_t)k * kNCH + t] = pw[k];
            }
            uzero[(size_t)5 * kNCH + t] = pw[4];
            p0=pw[0]; p1=pw[1]; p2=pw[2]; p3=pw[3]; p4=pw[4];
        }
        float acc4, acc2;
        {
            float q0=p0*p0, q1=p1*p1, q2=p2*p2, q3=p3*p3, q4=p4*p4;
            acc4 = 7.0f*q0*q0 + 32.0f*q1*q1 + 32.0f*q3*q3 + 14.0f*q4*q4 + 32.0f*q4*q4;
            acc2 = q2;
        }
        float f0, f1, f2, f3;
        {
            float i1 = rcp_nr(0.2f), i2 = rcp_nr(0.3f), i3 = rcp_nr(0.4f), i4 = rcp_nr(0.5f);
            f0 = fmaf(i1, fmaf(ll1, i1, -1.0f), negE);
            f1 = fmaf(i2, fmaf(ll1, i2, -1.0f), negE);
            f2 = fmaf(i3, fmaf(ll1, i3, -1.0f), negE);
            f3 = fmaf(i4, fmaf(ll1, i4, -1.0f), negE);
        }
        float* ptr = uzero + (size_t)6 * kNCH + t;
        #pragma unroll 4
        for (int j = 5; j <= 98; ++j) {
            float rm = fmaf((float)j, 0.1f, 0.1f);
            float ri = rcp_nr(rm);
            float f4 = fmaf(ri, fmaf(ll1, ri, -1.0f), negE);
            float iv = rcp_nr(fmaf(-kC, f4, 1.0f));
            float a  = fmaf(kC  * f0, iv, -1.0f);
            float b  = fmaf(kK1 * f1, iv,  2.0f);
            float cc = fmaf(kK2 * f2, iv, -2.0f);
            float d  = fmaf(kK1 * f3, iv,  2.0f);
            float nw = fmaf(d, p4, fmaf(cc, p3, fmaf(b, p2, a * p1)));
            *ptr = nw; ptr += kNCH;
            float v2 = nw*nw, v4 = v2*v2;
            if (j <= 94) {
                int m = (j + 1) & 3;
                if (m == 2)      acc2 += v2;
                else if (m == 0) acc4 += 14.0f * v4;
                else             acc4 += 32.0f * v4;
            } else if (j == 95) {
                acc4 += 7.0f * v4;
            }
            f0 = f1; f1 = f2; f2 = f3; f3 = f4;
            p0 = p1; p1 = p2; p2 = p3; p3 = p4; p4 = nw;
        }
        float integ = fmaf(12.0f, acc2, acc4) * (2.0f * 0.1f / 45.0f);
        float deriv = fmaf(25.0f, p4, fmaf(-48.0f, p3, fmaf(36.0f, p2,
                      fmaf(-16.0f, p1, 3.0f * p0)))) * (1.0f / 1.2f);
        ws[2 * kNCH + t] = deriv / p4;
        ws[3 * kNCH + t] = integ / (p4 * p4);
        return;
    }

    // ---------------- u_infty: segmented inward solve ----------------
    const int b = bid - kZeroBlocks;
    const int g = tid & 15;            // chain within block
    const int s = tid >> 4;            // segment index 0..15
    const int t = b * 16 + g;
    const int l  = t % 3;
    const int ei = t / 3;
    const float e = energy[ei], negE = -e;
    const float ll1 = (float)(l * (l + 1));
    const int jstart = 5 + 56 * s;     // seg s: steps j in [jstart, jstart+ns), ns=56 (54 for s=15)
    int j = jstart;

    // factor ring init: factors at steps jstart-4 .. jstart-1
    float F0, F1, F2, F3;
    {
        float i0 = rcp_nr(fmaf((float)(jstart - 4), -0.1f, 100.0f));
        float i1 = rcp_nr(fmaf((float)(jstart - 3), -0.1f, 100.0f));
        float i2 = rcp_nr(fmaf((float)(jstart - 2), -0.1f, 100.0f));
        float i3 = rcp_nr(fmaf((float)(jstart - 1), -0.1f, 100.0f));
        F0 = fmaf(i0, fmaf(ll1, i0, -1.0f), negE);
        F1 = fmaf(i1, fmaf(ll1, i1, -1.0f), negE);
        F2 = fmaf(i2, fmaf(ll1, i2, -1.0f), negE);
        F3 = fmaf(i3, fmaf(ll1, i3, -1.0f), negE);
    }
    const float ff0 = F0, ff1 = F1, ff2 = F2, ff3 = F3;

    float ca, cb, cc_, cd;
#define COEF(FA,FB,FC,FD) \
    { float rm = fmaf((float)j, -0.1f, 100.0f); \
      float ri = rcp_nr(rm); \
      float f4 = fmaf(ri, fmaf(ll1, ri, -1.0f), negE); \
      float iv = rcp_nr(fmaf(-kC, f4, 1.0f)); \
      ca  = fmaf(kC  * FA, iv, -1.0f); \
      cb  = fmaf(kK1 * FB, iv,  2.0f); \
      cc_ = fmaf(kK2 * FC, iv, -2.0f); \
      cd  = fmaf(kK1 * FD, iv,  2.0f); \
      FA = f4; }

    // ---- phase 1: 4x4 companion product (rows oldest-first, rotating names)
    float ra[4] = {1,0,0,0}, rb[4] = {0,1,0,0}, rc[4] = {0,0,1,0}, rd[4] = {0,0,0,1};
#define MSTEP(FA,FB,FC,FD,RA,RB,RC,RD) \
    { COEF(FA,FB,FC,FD) \
      RA[0] = fmaf(cd,RD[0], fmaf(cc_,RC[0], fmaf(cb,RB[0], ca*RA[0]))); \
      RA[1] = fmaf(cd,RD[1], fmaf(cc_,RC[1], fmaf(cb,RB[1], ca*RA[1]))); \
      RA[2] = fmaf(cd,RD[2], fmaf(cc_,RC[2], fmaf(cb,RB[2], ca*RA[2]))); \
      RA[3] = fmaf(cd,RD[3], fmaf(cc_,RC[3], fmaf(cb,RB[3], ca*RA[3]))); \
      ++j; }

    for (int it = 0; it < 13; ++it) {   // 52 steps
        MSTEP(F0,F1,F2,F3, ra,rb,rc,rd)
        MSTEP(F1,F2,F3,F0, rb,rc,rd,ra)
        MSTEP(F2,F3,F0,F1, rc,rd,ra,rb)
        MSTEP(F3,F0,F1,F2, rd,ra,rb,rc)
    }
    {
        float* dst = &sP[s][g][0];
        if (s < 15) {                   // +4 steps = 56, order restored
            MSTEP(F0,F1,F2,F3, ra,rb,rc,rd)
            MSTEP(F1,F2,F3,F0, rb,rc,rd,ra)
            MSTEP(F2,F3,F0,F1, rc,rd,ra,rb)
            MSTEP(F3,F0,F1,F2, rd,ra,rb,rc)
            #pragma unroll
            for (int c = 0; c < 4; ++c) {
                dst[c] = ra[c]; dst[4+c] = rb[c]; dst[8+c] = rc[c]; dst[12+c] = rd[c];
            }
        } else {                        // +2 steps = 54, logical order (rc,rd,ra,rb)
            MSTEP(F0,F1,F2,F3, ra,rb,rc,rd)
            MSTEP(F1,F2,F3,F0, rb,rc,rd,ra)
            #pragma unroll
            for (int c = 0; c < 4; ++c) {
                dst[c] = rc[c]; dst[4+c] = rd[c]; dst[8+c] = ra[c]; dst[12+c] = rb[c];
            }
        }
    }
    __syncthreads();

    // ---- phase 2: per-chain serial combine (lanes s==0, i.e. tid 0..15)
    if (s == 0) {
        const float se  = sqrtf(fabsf(e));
        const float rfc = (l == 0) ? 1.0f : ((l == 1) ? (1.0f/3.0f) : (1.0f/15.0f));
        const float rt1 = (l == 0) ? (1.0f/3.0f) : ((l == 1) ? (1.0f/5.0f) : (1.0f/7.0f));
        const float rt2 = (l == 0) ? (1.0f/30.0f) : ((l == 1) ? (1.0f/70.0f) : (1.0f/126.0f));
        float pw[5];
        #pragma unroll
        for (int k = 0; k < 5; ++k) {
            float rinf = 99.6f + 0.1f * (float)k;
            float x  = rinf * se;
            float xl = (l == 0) ? 1.0f : ((l == 1) ? x : x * x);
            float h  = x * x * 0.5f;
            pw[k] = rinf * (xl * rfc * (1.0f + h * rt1 + (h * h) * rt2));
        }
        uinf[(size_t)899 * kNCH + t] = pw[4];
        float st0 = pw[1], st1 = pw[2], st2 = pw[3], st3 = pw[4];
        for (int ss = 0; ss < 16; ++ss) {
            sSt[ss][g][0] = st0; sSt[ss][g][1] = st1;
            sSt[ss][g][2] = st2; sSt[ss][g][3] = st3;
            const float* P = &sP[ss][g][0];
            float n0 = fmaf(P[ 3],st3, fmaf(P[ 2],st2, fmaf(P[ 1],st1, P[ 0]*st0)));
            float n1 = fmaf(P[ 7],st3, fmaf(P[ 6],st2, fmaf(P[ 5],st1, P[ 4]*st0)));
            float n2 = fmaf(P[11],st3, fmaf(P[10],st2, fmaf(P[ 9],st1, P[ 8]*st0)));
            float n3 = fmaf(P[15],st3, fmaf(P[14],st2, fmaf(P[13],st1, P[12]*st0)));
            st0 = n0; st1 = n1; st2 = n2; st3 = n3;
        }
    }
    __syncthreads();

    // ---- phase 3: replay from exact segment-initial state
    j = jstart;
    F0 = ff0; F1 = ff1; F2 = ff2; F3 = ff3;
    float p0 = sSt[s][g][0], p1 = sSt[s][g][1], p2 = sSt[s][g][2], p3 = sSt[s][g][3];
    float acc4 = 0.0f, acc2 = 0.0f;
    float* ptr = uinf + (size_t)(903 - jstart) * kNCH + t;
#define RSTEP(FA,FB,FC,FD,PA,PB,PC,PD) \
    { COEF(FA,FB,FC,FD) \
      float nw = fmaf(cd,PD, fmaf(cc_,PC, fmaf(cb,PB, ca*PA))); \
      PA = nw; *ptr = nw; ptr -= kNCH; \
      float v2 = nw*nw, v4 = v2*v2; \
      if (j >= 8) { int m = j & 3; \
        if (m == 1) acc2 += v2; \
        else acc4 += ((m == 3) ? 14.0f : 32.0f) * v4; } \
      else if (j == 7) acc4 += 7.0f * v4; \
      ++j; }

    for (int it = 0; it < 13; ++it) {   // 52 steps
        RSTEP(F0,F1,F2,F3, p0,p1,p2,p3)
        RSTEP(F1,F2,F3,F0, p1,p2,p3,p0)
        RSTEP(F2,F3,F0,F1, p2,p3,p0,p1)
        RSTEP(F3,F0,F1,F2, p3,p0,p1,p2)
    }
    float h0 = 0.0f;
    if (s < 15) {
        RSTEP(F0,F1,F2,F3, p0,p1,p2,p3)
        RSTEP(F1,F2,F3,F0, p1,p2,p3,p0)
        RSTEP(F2,F3,F0,F1, p2,p3,p0,p1)
        RSTEP(F3,F0,F1,F2, p3,p0,p1,p2)
    } else {
        RSTEP(F0,F1,F2,F3, p0,p1,p2,p3)   // j=897 -> w897 into p0
        h0 = p1;                           // w894 (about to be overwritten)
        RSTEP(F1,F2,F3,F0, p1,p2,p3,p0)   // j=898 -> w898 into p1
        // window now: h0=w894, p2=w895, p3=w896, p0=w897, p1=w898
    }
    sR4[s][g] = acc4;
    sR2[s][g] = acc2;
    __syncthreads();

    if (s == 15) {
        float a4 = 0.0f, a2 = 0.0f;
        #pragma unroll
        for (int ss = 0; ss < 16; ++ss) { a4 += sR4[ss][g]; a2 += sR2[ss][g]; }
        float h1 = p2, h2 = p3, h3 = p0, h4 = p1;
        uinf[(size_t)0 * kNCH + t] = h0;
        uinf[(size_t)1 * kNCH + t] = h1;
        uinf[(size_t)2 * kNCH + t] = h2;
        uinf[(size_t)3 * kNCH + t] = h3;
        uinf[(size_t)4 * kNCH + t] = h4;
        float q0 = h0*h0, q1 = h1*h1, q2 = h2*h2, q3 = h3*h3, q4 = h4*h4;
        a4 += 7.0f*q0*q0 + 32.0f*q1*q1 + 32.0f*q3*q3 + 14.0f*q4*q4;
        a2 += q2;
        float integ = fmaf(12.0f, a2, a4) * (2.0f * 0.1f / 45.0f);
        float deriv = fmaf(25.0f, h0, fmaf(-48.0f, h1, fmaf(36.0f, h2,
                      fmaf(-16.0f, h3, 3.0f * h4)))) * (1.0f / 1.2f);
        ws[t]        = deriv / h0;            // lfunc_out (pre energy-reversal)
        ws[kNCH + t] = integ / (h0 * h0);     // integ_out / u_infty[0]^2
    }
#undef RSTEP
#undef MSTEP
#undef COEF
}

__global__ __launch_bounds__(256) void final_kernel(const float* __restrict__ energy,
                                                    const float* __restrict__ ws,
                                                    float* __restrict__ out)
{
    int t = (int)blockIdx.x * 256 + (int)threadIdx.x;
    if (t >= kNCH) return;
    int l = t % 3, ei = t / 3;
    float lf_out = ws[(kNE - 1 - ei) * 3 + l];   // energy-axis reversed
    float lf_in  = ws[2 * kNCH + t];
    float den    = ws[kNCH + t] + ws[3 * kNCH + t];
    out[t] = energy[ei] - (lf_out - lf_in) / den;
}

extern "C" void kernel_launch(void* const* d_in, const int* in_sizes, int n_in,
                              void* d_out, int out_size, void* d_ws, size_t ws_size,
                              hipStream_t stream) {
    (void)in_sizes; (void)n_in; (void)out_size; (void)ws_size;
    const float* energy = (const float*)d_in[0];
    float* out = (float*)d_out;
    float* ws  = (float*)d_ws;   // 4*12288 floats = 192 KB scratch
    solve_kernel<<<kZeroBlocks + kInfBlocks, 256, 0, stream>>>(energy, out, ws);
    final_kernel<<<kNCH / 256, 256, 0, stream>>>(energy, ws, out);
}